// Round 1
// baseline (275.544 us; speedup 1.0000x reference)
//
#include <hip/hip_runtime.h>
#include <hip/hip_bf16.h>
#include <cstdint>
#include <cstddef>

typedef unsigned short u16;
typedef unsigned int   u32;
typedef __attribute__((ext_vector_type(8))) short short8;
typedef __attribute__((ext_vector_type(4))) short short4v;
typedef __attribute__((ext_vector_type(4))) float f32x4;

#define D_MODEL 1024
#define NH      16
#define HD      64
#define SEQ     2048
#define BATCH   2
#define MTOT    (BATCH*SEQ)   // 4096
#define NQKV    3072

__device__ __forceinline__ float bf2f(u16 h){ u32 u = ((u32)h) << 16; float f; __builtin_memcpy(&f, &u, 4); return f; }
__device__ __forceinline__ u16 f2bf(float f){ u32 u; __builtin_memcpy(&u, &f, 4); u = (u + 0x7FFFu + ((u >> 16) & 1u)) >> 16; return (u16)u; }

__device__ __forceinline__ void gload16(const void* g, void* s){
  __builtin_amdgcn_global_load_lds((const __attribute__((address_space(1))) void*)g,
                                   (__attribute__((address_space(3))) void*)s, 16, 0, 0);
}

// ---------------- convert fp32 -> bf16 (x, Wq|Wk|Wv packed, Wo) ----------------
__global__ __launch_bounds__(256) void convert_kernel(
    const float4* __restrict__ x, const float4* __restrict__ wq, const float4* __restrict__ wk,
    const float4* __restrict__ wv, const float4* __restrict__ wo,
    u16* __restrict__ xb, u16* __restrict__ wqkvb, u16* __restrict__ wob)
{
  int i = blockIdx.x * 256 + threadIdx.x;           // 2,097,152 units of 4 floats
  const float4* src; u16* dst;
  if (i < 1048576) {                                // x: 4,194,304 elems
    src = x + i; dst = xb + (size_t)i * 4;
  } else if (i < 1835008) {                         // Wq,Wk,Wv: 3 x 1,048,576
    int j = i - 1048576;
    int w = j >> 18;                                // which W (262144 units each)
    int e = j & 262143;
    src = (w == 0 ? wq : (w == 1 ? wk : wv)) + e;
    dst = wqkvb + (size_t)w * 1048576 + (size_t)e * 4;
  } else {                                          // Wo
    int j = i - 1835008;
    src = wo + j; dst = wob + (size_t)j * 4;
  }
  float4 v = *src;
  u32 lo = (u32)f2bf(v.x) | ((u32)f2bf(v.y) << 16);
  u32 hi = (u32)f2bf(v.z) | ((u32)f2bf(v.w) << 16);
  u32* d32 = (u32*)dst;
  d32[0] = lo; d32[1] = hi;
}

// ---------------- RoPE cos/sin table: tab[pos*32+p] = (cos, sin) ----------------
__global__ __launch_bounds__(256) void rope_table_kernel(float2* __restrict__ tab){
  int i = blockIdx.x * 256 + threadIdx.x;           // 65536 = 2048 pos * 32 pairs
  int pos = i >> 5, p = i & 31;
  // inv_freq = theta^(-p/32), theta = 10000 ; ln(10000) = 9.210340371976184
  float freq = __expf(-(float)p * (9.210340371976184f / 32.0f));
  float ang = (float)pos * freq;
  float s, c;
  sincosf(ang, &s, &c);
  tab[i] = make_float2(c, s);
}

// ---------------- RoPE apply in-place on Q,K columns of QKV ----------------
__global__ __launch_bounds__(256) void rope_apply_kernel(
    u16* __restrict__ qkv, const int* __restrict__ tpos, const float2* __restrict__ tab)
{
  int tid = blockIdx.x * 256 + threadIdx.x;         // 4096 rows * 1024 pairs
  int m    = tid >> 10;
  int pp   = tid & 1023;
  int slot = pp >> 5;                               // 0..31 (16 Q heads then 16 K heads)
  int p    = pp & 31;
  int col  = slot * 64 + 2 * p;
  u32* addr = (u32*)(qkv + (size_t)m * NQKV + col);
  u32 v = *addr;
  float x1 = bf2f((u16)(v & 0xffff));
  float x2 = bf2f((u16)(v >> 16));
  int pos = tpos[m];
  float2 cs = tab[(size_t)pos * 32 + p];
  float r1 = x1 * cs.x - x2 * cs.y;
  float r2 = x1 * cs.y + x2 * cs.x;
  *addr = (u32)f2bf(r1) | ((u32)f2bf(r2) << 16);
}

// ---------------- bf16 GEMM, C[m][n] = sum_k A[m][k]*B[n][k]  (B^T layout) ------
// m97 structure: 128x128 tile, 4 waves (2x2 of 64x64), BK=32, global_load_lds.
template<typename OutT>
__global__ __launch_bounds__(256) void gemm_bt(
    const u16* __restrict__ A, const u16* __restrict__ B, OutT* __restrict__ C,
    int M, int N, int K)
{
  __shared__ __align__(16) u16 As[128 * 32];
  __shared__ __align__(16) u16 Bs[128 * 32];
  int t = threadIdx.x;
  int w = t >> 6, l = t & 63, g = l >> 4, c = l & 15;
  int wr = w >> 1, wc = w & 1;
  int bm = blockIdx.y * 128, bn = blockIdx.x * 128;

  const u16* aS0 = A + (size_t)(bm + (t >> 2)) * K + (t & 3) * 8;
  const u16* aS1 = aS0 + (size_t)64 * K;
  const u16* bS0 = B + (size_t)(bn + (t >> 2)) * K + (t & 3) * 8;
  const u16* bS1 = bS0 + (size_t)64 * K;
  char* ldsA0 = (char*)As + w * 1024;
  char* ldsA1 = (char*)As + 4096 + w * 1024;
  char* ldsB0 = (char*)Bs + w * 1024;
  char* ldsB1 = (char*)Bs + 4096 + w * 1024;

  f32x4 z = {0.f, 0.f, 0.f, 0.f};
  f32x4 acc[4][4];
  #pragma unroll
  for (int i = 0; i < 4; i++)
    #pragma unroll
    for (int j = 0; j < 4; j++) acc[i][j] = z;

  for (int kk = 0; kk < K; kk += 32) {
    gload16(aS0 + kk, ldsA0);
    gload16(aS1 + kk, ldsA1);
    gload16(bS0 + kk, ldsB0);
    gload16(bS1 + kk, ldsB1);
    asm volatile("s_waitcnt vmcnt(0)" ::: "memory");
    __syncthreads();

    short8 af[4], bfr[4];
    #pragma unroll
    for (int i = 0; i < 4; i++)
      af[i] = *(const short8*)&As[(size_t)(wr * 64 + i * 16 + c) * 32 + g * 8];
    #pragma unroll
    for (int j = 0; j < 4; j++)
      bfr[j] = *(const short8*)&Bs[(size_t)(wc * 64 + j * 16 + c) * 32 + g * 8];
    #pragma unroll
    for (int i = 0; i < 4; i++)
      #pragma unroll
      for (int j = 0; j < 4; j++)
        acc[i][j] = __builtin_amdgcn_mfma_f32_16x16x32_bf16(af[i], bfr[j], acc[i][j], 0, 0, 0);
    __syncthreads();
  }

  #pragma unroll
  for (int i = 0; i < 4; i++) {
    int row0 = bm + wr * 64 + i * 16 + 4 * g;
    #pragma unroll
    for (int j = 0; j < 4; j++) {
      int col = bn + wc * 64 + j * 16 + c;
      #pragma unroll
      for (int r = 0; r < 4; r++) {
        float v = acc[i][j][r];
        size_t idx = (size_t)(row0 + r) * N + col;
        if constexpr (sizeof(OutT) == 2) ((u16*)C)[idx] = f2bf(v);
        else                             ((float*)C)[idx] = v;
      }
    }
  }
}

// ---------------- causal flash attention, swapped-QK^T, O^T accumulation --------
__global__ __launch_bounds__(256) void attn_kernel(
    const u16* __restrict__ qkv, u16* __restrict__ ctx)
{
  int bh = blockIdx.y; int b = bh >> 4, h = bh & 15;
  int w = threadIdx.x >> 6, l = threadIdx.x & 63, g = l >> 4, c = l & 15;
  int qblk = (int)gridDim.x - 1 - (int)blockIdx.x;   // heavy blocks dispatch first
  int q0 = qblk * 64 + w * 16;
  const u16* base = qkv + (size_t)b * SEQ * NQKV;
  const u16* Qb = base + h * HD;
  const u16* Kb = base + D_MODEL + h * HD;
  const u16* Vb = base + 2 * D_MODEL + h * HD;

  int q = q0 + c;
  short8 qf0 = *(const short8*)(Qb + (size_t)q * NQKV + g * 8);
  short8 qf1 = *(const short8*)(Qb + (size_t)q * NQKV + 32 + g * 8);

  f32x4 z = {0.f, 0.f, 0.f, 0.f};
  f32x4 o[4] = {z, z, z, z};
  float mrun = -1e30f, lrun = 0.f;

  int ntiles = (q0 >> 4) + 1;
  for (int kt = 0; kt < ntiles; ++kt) {
    int k0 = kt << 4;
    const u16* kr = Kb + (size_t)(k0 + c) * NQKV;
    short8 kf0 = *(const short8*)(kr + g * 8);
    short8 kf1 = *(const short8*)(kr + 32 + g * 8);
    f32x4 s4 = z;
    s4 = __builtin_amdgcn_mfma_f32_16x16x32_bf16(kf0, qf0, s4, 0, 0, 0);  // S^T[k][q]
    s4 = __builtin_amdgcn_mfma_f32_16x16x32_bf16(kf1, qf1, s4, 0, 0, 0);

    float sc[4];
    #pragma unroll
    for (int r = 0; r < 4; r++) {
      int k = k0 + 4 * g + r;
      sc[r] = (k <= q) ? s4[r] * 0.125f : -1e30f;
    }
    float tm = fmaxf(fmaxf(sc[0], sc[1]), fmaxf(sc[2], sc[3]));
    tm = fmaxf(tm, __shfl_xor(tm, 16));
    tm = fmaxf(tm, __shfl_xor(tm, 32));
    float mnew = fmaxf(mrun, tm);
    float p0 = __expf(sc[0] - mnew), p1 = __expf(sc[1] - mnew);
    float p2 = __expf(sc[2] - mnew), p3 = __expf(sc[3] - mnew);
    float rs = (p0 + p1) + (p2 + p3);
    rs += __shfl_xor(rs, 16);
    rs += __shfl_xor(rs, 32);
    float alpha = __expf(mrun - mnew);
    lrun = lrun * alpha + rs;
    mrun = mnew;
    #pragma unroll
    for (int dt = 0; dt < 4; dt++) {
      o[dt][0] *= alpha; o[dt][1] *= alpha; o[dt][2] *= alpha; o[dt][3] *= alpha;
    }
    short4v pf;
    pf[0] = (short)f2bf(p0); pf[1] = (short)f2bf(p1);
    pf[2] = (short)f2bf(p2); pf[3] = (short)f2bf(p3);
    #pragma unroll
    for (int dt = 0; dt < 4; dt++) {
      short4v vf;
      #pragma unroll
      for (int bb = 0; bb < 4; bb++)
        vf[bb] = (short)Vb[(size_t)(k0 + 4 * g + bb) * NQKV + dt * 16 + c];
      // O^T[d][q] += V^T[d][k] * P^T[k][q]
      o[dt] = __builtin_amdgcn_mfma_f32_16x16x16bf16_1k(vf, pf, o[dt], 0, 0, 0);
    }
  }

  float inv = 1.0f / lrun;
  size_t obase = ((size_t)b * SEQ + q) * D_MODEL + h * HD;
  #pragma unroll
  for (int dt = 0; dt < 4; dt++) {
    u32 lo = (u32)f2bf(o[dt][0] * inv) | ((u32)f2bf(o[dt][1] * inv) << 16);
    u32 hi = (u32)f2bf(o[dt][2] * inv) | ((u32)f2bf(o[dt][3] * inv) << 16);
    u32* dp = (u32*)(ctx + obase + dt * 16 + 4 * g);
    dp[0] = lo; dp[1] = hi;
  }
}

// ---------------- launch ----------------
extern "C" void kernel_launch(void* const* d_in, const int* in_sizes, int n_in,
                              void* d_out, int out_size, void* d_ws, size_t ws_size,
                              hipStream_t stream)
{
  const float* x   = (const float*)d_in[0];
  const int*  tpos = (const int*) d_in[1];
  const float* Wq  = (const float*)d_in[2];
  const float* Wk  = (const float*)d_in[3];
  const float* Wv  = (const float*)d_in[4];
  const float* Wo  = (const float*)d_in[5];

  char* ws = (char*)d_ws;
  u16*    xb    = (u16*)(ws);                   //  8,388,608 B
  u16*    wqkvb = (u16*)(ws + 8388608);         //  6,291,456 B
  u16*    wob   = (u16*)(ws + 14680064);        //  2,097,152 B
  u16*    qkvb  = (u16*)(ws + 16777216);        // 25,165,824 B
  u16*    ctx   = (u16*)(ws + 41943040);        //  8,388,608 B
  float2* tab   = (float2*)(ws + 50331648);     //    524,288 B  (total ~48.5 MB)

  convert_kernel<<<8192, 256, 0, stream>>>(
      (const float4*)x, (const float4*)Wq, (const float4*)Wk, (const float4*)Wv, (const float4*)Wo,
      xb, wqkvb, wob);
  rope_table_kernel<<<256, 256, 0, stream>>>(tab);
  gemm_bt<u16><<<dim3(NQKV / 128, MTOT / 128), 256, 0, stream>>>(xb, wqkvb, qkvb, MTOT, NQKV, D_MODEL);
  rope_apply_kernel<<<16384, 256, 0, stream>>>(qkvb, tpos, tab);
  attn_kernel<<<dim3(SEQ / 64, BATCH * NH), 256, 0, stream>>>(qkvb, ctx);
  gemm_bt<float><<<dim3(D_MODEL / 128, MTOT / 128), 256, 0, stream>>>(ctx, wob, (float*)d_out, MTOT, D_MODEL, D_MODEL);
}